// Round 3
// baseline (1972.935 us; speedup 1.0000x reference)
//
#include <hip/hip_runtime.h>
#include <math.h>

#define BB 4
#define SS 256
#define DD 300
#define DP 304   // DD padded to multiple of 16
#define EE 128
#define LL 20
#define H3 384
#define D2 256   // 2E
#define D12 1536 // 12E

typedef __attribute__((ext_vector_type(8)))  short short8;
typedef __attribute__((ext_vector_type(16))) float f32x16;
typedef __attribute__((ext_vector_type(4)))  float f32x4;
typedef __attribute__((ext_vector_type(4)))  unsigned int u32x4;

__device__ __forceinline__ float tanh_fast(float x){
  float e = __expf(2.f*x);
  return 1.f - 2.f/(e+1.f);
}
__device__ __forceinline__ float sigmoidf_(float x){ return 1.f/(1.f+__expf(-x)); }
__device__ __forceinline__ float bf16_to_f(unsigned u){ return __builtin_bit_cast(float, u<<16); }
__device__ __forceinline__ float bf16hi_to_f(unsigned u){ return __builtin_bit_cast(float, u & 0xFFFF0000u); }
__device__ __forceinline__ unsigned bf16_rne(float f){
  unsigned u = __builtin_bit_cast(unsigned, f);
  return (u + 0x7FFFu + ((u>>16)&1u)) >> 16;
}
__device__ __forceinline__ unsigned pack_bf16x2(float lo, float hi){
  return bf16_rne(lo) | (bf16_rne(hi)<<16);
}

// ---------------- f32 -> bf16 (RNE), 2 elems/thread ----------------
__global__ void k_cvt_bf16(const float* __restrict__ src, unsigned short* __restrict__ dst, int n2){
  int i = blockIdx.x*blockDim.x + threadIdx.x;
  if (i < n2){
    float2 f = *(const float2*)(src + 2*i);
    *(unsigned*)(dst + 2*i) = pack_bf16x2(f.x, f.y);
  }
}

// ---------------- fused weight conversion (13 segments, K-padding aware) ----------------
struct CvtSeg { const float* src; unsigned short* dst; int rows, Ks, Kd; };
struct CvtArgs { CvtSeg s[13]; };
__global__ void k_cvt_weights(CvtArgs a){
  CvtSeg sg = a.s[blockIdx.y];
  int p = blockIdx.x*256 + threadIdx.x;          // dst pair index
  int Kd2 = sg.Kd>>1;
  int npairs = sg.rows*Kd2;
  if (p >= npairs) return;
  int row = p/Kd2, kk = (p - row*Kd2)*2;
  float f0 = (kk   < sg.Ks)? sg.src[(size_t)row*sg.Ks+kk  ] : 0.f;
  float f1 = (kk+1 < sg.Ks)? sg.src[(size_t)row*sg.Ks+kk+1] : 0.f;
  *(unsigned*)(sg.dst + (size_t)row*sg.Kd + kk) = pack_bf16x2(f0,f1);
}

// ---------------- embedding gather -> padded bf16 ----------------
__global__ void k_embed(const int* __restrict__ inp, const float* __restrict__ emb,
                        unsigned short* __restrict__ xb){
  int row = blockIdx.x;            // b*S+s
  int idx = inp[row];
  const float* src = emb + (size_t)idx*DD;
  unsigned short* dst = xb + (size_t)row*DP;
  int p = threadIdx.x;             // pair index, 152 pairs
  if (p < DP/2){
    float f0 = (2*p   < DD)? src[2*p  ] : 0.f;
    float f1 = (2*p+1 < DD)? src[2*p+1] : 0.f;
    *(unsigned*)(dst + 2*p) = pack_bf16x2(f0,f1);
  }
}

// ---------------- init gx pair with input-projection biases ----------------
__global__ void k_init2(float* __restrict__ gf, const float* __restrict__ bf,
                        float* __restrict__ gb, const float* __restrict__ bb){
  int row = blockIdx.x, n = threadIdx.x;   // block = H3 threads
  gf[(size_t)row*H3+n] = bf[n];
  gb[(size_t)row*H3+n] = bb[n];
}

// ---------------- bf16 MFMA matmul: out[M,N] (+)= X[M,K] @ W[N,K]^T ----------------
__global__ __launch_bounds__(64) void k_mmbf(
    const unsigned short* __restrict__ X, const unsigned short* __restrict__ W,
    const float* __restrict__ bias, float* __restrict__ out,
    int N, int K, int kspan){
  int lane=threadIdx.x, col=lane&31, half=lane>>5;
  int n0=blockIdx.x*32, m0=blockIdx.y*64;
  int ks=blockIdx.z*kspan, ke=ks+kspan; if (ke>K) ke=K;
  const unsigned short* pa0 = X + (size_t)(m0+col)*K + half*8;
  const unsigned short* pa1 = pa0 + (size_t)32*K;
  const unsigned short* pb  = W + (size_t)(n0+col)*K + half*8;
  f32x16 acc0={}, acc1={};
  #pragma unroll 2
  for (int k=ks;k<ke;k+=16){
    short8 a0=__builtin_bit_cast(short8, *(const uint4*)(pa0+k));
    short8 a1=__builtin_bit_cast(short8, *(const uint4*)(pa1+k));
    short8 bv=__builtin_bit_cast(short8, *(const uint4*)(pb +k));
    acc0=__builtin_amdgcn_mfma_f32_32x32x16_bf16(a0,bv,acc0,0,0,0);
    acc1=__builtin_amdgcn_mfma_f32_32x32x16_bf16(a1,bv,acc1,0,0,0);
  }
  int cn = n0+col;
  if (gridDim.z==1){
    float bn = bias? bias[cn] : 0.f;
    #pragma unroll
    for (int r=0;r<16;r++){
      int row=(r&3)+8*(r>>2)+4*half;
      out[(size_t)(m0+row)*N+cn]    = acc0[r]+bn;
      out[(size_t)(m0+32+row)*N+cn] = acc1[r]+bn;
    }
  } else {
    #pragma unroll
    for (int r=0;r<16;r++){
      int row=(r&3)+8*(r>>2)+4*half;
      atomicAdd(&out[(size_t)(m0+row)*N+cn],    acc0[r]);
      atomicAdd(&out[(size_t)(m0+32+row)*N+cn], acc1[r]);
    }
  }
}

// ---------------- GRU scan: MFMA recurrence ----------------
// One block per direction, 256 threads = 4 waves, all 4 batches in MFMA M dim.
// Per step: scores[4,384] = h_bf16[4,128] @ Whh^T via mfma_f32_16x16x32_bf16.
// Wave w owns column-triples {r,r+128,r+256} for r in [16w,16w+16) and +64,
// so all 3 gate pre-activations for a given h-row land in the SAME wave,
// lanes 0-15, reg index = batch (C layout: col=lane&15, row=reg). Gates are
// computed fully in-register; h round-trips through a tiny double-buffered
// LDS fragment buffer laid out exactly in MFMA-A order (4 conflict-free
// ds_read_b128 per wave per step). Weights live in 96 VGPRs as MFMA B-frags
// (pinned with keep-alive asm so the compiler cannot rematerialize them —
// rounds 0-2 all lost ~1500cy/step re-fetching spilled weights).
__global__ __launch_bounds__(256, 1) void k_gru_scan(
                          const float* __restrict__ gxf, const float* __restrict__ gxb,
                          const float* __restrict__ whhf, const float* __restrict__ whhb,
                          const float* __restrict__ bhhf, const float* __restrict__ bhhb,
                          const float* __restrict__ h0,
                          float* __restrict__ out,
                          float* __restrict__ hT){
  int dir = blockIdx.x, tid = threadIdx.x;
  const float* gx  = dir? gxb : gxf;
  const float* whh = dir? whhb : whhf;
  const float* bhh = dir? bhhb : bhhf;
  int w = tid>>6, lane = tid&63;
  int q = lane>>4, c = lane&15;          // k-quarter, col-in-tile
  int r0 = w*16 + c, r1 = r0 + 64;

  // ---- B fragments: 6 tiles x 4 k-tiles, bf16, register-resident ----
  // tiles: group0 (rows r0): {w, w+8, w+16} -> r/z/n ; group1 (rows r1): {w+4, w+12, w+20}
  short8 bfr[6][4];
  {
    int tiles[6] = {w, w+8, w+16, w+4, w+12, w+20};
    #pragma unroll
    for (int ti=0; ti<6; ti++){
      int col = tiles[ti]*16 + c;
      const float* wr = whh + (size_t)col*EE + q*8;
      #pragma unroll
      for (int kt=0; kt<4; kt++){
        float4 f0 = *(const float4*)(wr + kt*32);
        float4 f1 = *(const float4*)(wr + kt*32 + 4);
        u32x4 pk;
        pk.x = pack_bf16x2(f0.x, f0.y); pk.y = pack_bf16x2(f0.z, f0.w);
        pk.z = pack_bf16x2(f1.x, f1.y); pk.w = pack_bf16x2(f1.z, f1.w);
        asm volatile("" : "+v"(pk));   // opaque: no remat, stays in VGPRs
        bfr[ti][kt] = __builtin_bit_cast(short8, pk);
      }
    }
  }

  // hfrag: [buf 2][group 16][row 16][4 words], group stride 68 words (pad 4)
  // k-index -> (group = k>>3, word = b*4 + (k&7)>>1). A-read: lane l reads
  // group kt*4+(l>>4), row l&15 -> one 16B-aligned ds_read_b128, ~conflict-free.
  __shared__ float hfragw[2*1088];
  for (int i=tid; i<2*1088; i+=256) hfragw[i] = 0.f;

  float br0=0,bz0=0,bn0=0,br1=0,bz1=0,bn1=0;
  float hp0[4]={0,0,0,0}, hp1[4]={0,0,0,0};
  if (lane < 16){
    br0=bhh[r0]; bz0=bhh[r0+EE]; bn0=bhh[r0+2*EE];
    br1=bhh[r1]; bz1=bhh[r1+EE]; bn1=bhh[r1+2*EE];
    #pragma unroll
    for (int b=0;b<4;b++){
      hp0[b] = h0? h0[((size_t)dir*BB+b)*EE + r0] : 0.f;
      hp1[b] = h0? h0[((size_t)dir*BB+b)*EE + r1] : 0.f;
    }
  }
  // pack h0 into buf 0 (shfl outside the even-lane branch)
  {
    float* hw = &hfragw[0];
    int g0 = 2*w + (c>>3);
    #pragma unroll
    for (int b=0;b<4;b++){
      float o0 = __shfl_xor(hp0[b], 1);
      float o1 = __shfl_xor(hp1[b], 1);
      if (lane<16 && (c&1)==0){
        *(unsigned*)&hw[(g0  )*68 + b*4 + ((c&7)>>1)] = pack_bf16x2(hp0[b], o0);
        *(unsigned*)&hw[(g0+8)*68 + b*4 + ((c&7)>>1)] = pack_bf16x2(hp1[b], o1);
      }
    }
  }
  __syncthreads();

  for (int t=0; t<SS; t++){
    int s = dir? (SS-1-t) : t;
    const float* hb = &hfragw[(t&1)*1088];
    // ---- A fragments (current h) ----
    short8 afr[4];
    #pragma unroll
    for (int kt=0; kt<4; kt++)
      afr[kt] = __builtin_bit_cast(short8, *(const u32x4*)&hb[(kt*4+q)*68 + c*4]);
    // ---- gx prefetch (consumed after MFMA; latency hides under it) ----
    float gxv[6][4];
    if (lane<16){
      #pragma unroll
      for (int b=0;b<4;b++){
        const float* g0 = gx + ((size_t)b*SS+s)*H3;
        gxv[0][b]=g0[r0]; gxv[1][b]=g0[r0+EE]; gxv[2][b]=g0[r0+2*EE];
        gxv[3][b]=g0[r1]; gxv[4][b]=g0[r1+EE]; gxv[5][b]=g0[r1+2*EE];
      }
    }
    // ---- MFMA: 24 per wave ----
    f32x4 aR0={},aZ0={},aN0={},aR1={},aZ1={},aN1={};
    #pragma unroll
    for (int kt=0; kt<4; kt++){
      aR0 = __builtin_amdgcn_mfma_f32_16x16x32_bf16(afr[kt], bfr[0][kt], aR0,0,0,0);
      aZ0 = __builtin_amdgcn_mfma_f32_16x16x32_bf16(afr[kt], bfr[1][kt], aZ0,0,0,0);
      aN0 = __builtin_amdgcn_mfma_f32_16x16x32_bf16(afr[kt], bfr[2][kt], aN0,0,0,0);
      aR1 = __builtin_amdgcn_mfma_f32_16x16x32_bf16(afr[kt], bfr[3][kt], aR1,0,0,0);
      aZ1 = __builtin_amdgcn_mfma_f32_16x16x32_bf16(afr[kt], bfr[4][kt], aZ1,0,0,0);
      aN1 = __builtin_amdgcn_mfma_f32_16x16x32_bf16(afr[kt], bfr[5][kt], aN1,0,0,0);
    }
    // ---- gates (lanes 0-15; reg index = batch) ----
    float h20[4], h21[4];
    if (lane<16){
      #pragma unroll
      for (int b=0;b<4;b++){
        float rg = sigmoidf_(gxv[0][b] + aR0[b] + br0);
        float zg = sigmoidf_(gxv[1][b] + aZ0[b] + bz0);
        float ng = tanh_fast (gxv[2][b] + rg*(aN0[b] + bn0));
        h20[b] = (1.f-zg)*ng + zg*hp0[b]; hp0[b] = h20[b];
        float rg1 = sigmoidf_(gxv[3][b] + aR1[b] + br1);
        float zg1 = sigmoidf_(gxv[4][b] + aZ1[b] + bz1);
        float ng1 = tanh_fast (gxv[5][b] + rg1*(aN1[b] + bn1));
        h21[b] = (1.f-zg1)*ng1 + zg1*hp1[b]; hp1[b] = h21[b];
        out[((size_t)b*SS+s)*D2 + dir*EE + r0] = h20[b];
        out[((size_t)b*SS+s)*D2 + dir*EE + r1] = h21[b];
      }
    }
    // ---- write next-step A operand into the other buffer ----
    {
      float* hw = &hfragw[((t+1)&1)*1088];
      int g0 = 2*w + (c>>3);
      #pragma unroll
      for (int b=0;b<4;b++){
        float o0 = __shfl_xor(h20[b], 1);
        float o1 = __shfl_xor(h21[b], 1);
        if (lane<16 && (c&1)==0){
          *(unsigned*)&hw[(g0  )*68 + b*4 + ((c&7)>>1)] = pack_bf16x2(h20[b], o0);
          *(unsigned*)&hw[(g0+8)*68 + b*4 + ((c&7)>>1)] = pack_bf16x2(h21[b], o1);
        }
      }
    }
    __syncthreads();
  }
  if (hT && lane<16){
    #pragma unroll
    for (int b=0;b<4;b++){
      hT[((size_t)dir*BB+b)*EE + r0] = hp0[b];
      hT[((size_t)dir*BB+b)*EE + r1] = hp1[b];
    }
  }
}

__global__ void k_copy_hq(const unsigned short* __restrict__ hqb, unsigned short* __restrict__ aggb){
  int row=blockIdx.x;
  aggb[(size_t)row*D12 + threadIdx.x] = hqb[(size_t)row*D2 + threadIdx.x];
}

// --------- block softmax over 256 values ---------
__device__ __forceinline__ void softmax256(float val, float* red, float* p){
  int tid=threadIdx.x;
  red[tid]=val; __syncthreads();
  for (int st=128; st>0; st>>=1){ if (tid<st) red[tid]=fmaxf(red[tid],red[tid+st]); __syncthreads(); }
  float mx=red[0]; __syncthreads();
  float ex=__expf(val-mx); red[tid]=ex; __syncthreads();
  for (int st=128; st>0; st>>=1){ if (tid<st) red[tid]+=red[tid+st]; __syncthreads(); }
  float inv=1.f/red[0];
  p[tid]=ex*inv; __syncthreads();
}

// ---------------- additive-style attention (ptc: +1, ptm: -1), bf16 out ----------------
__global__ __launch_bounds__(256) void k_attn_add(const float* __restrict__ A, const float* __restrict__ Bq,
                          const float* __restrict__ v, float sign,
                          const float* __restrict__ V, unsigned short* __restrict__ aggout, int off){
  __shared__ __align__(16) float bq[EE];
  __shared__ __align__(16) float vv[EE];
  __shared__ float p[SS]; __shared__ float red[SS];
  int q=blockIdx.x, b=blockIdx.y, tid=threadIdx.x;
  if (tid<EE){ bq[tid]=sign*Bq[((size_t)b*SS+q)*EE+tid]; vv[tid]=v[tid]; }
  __syncthreads();
  const float* Ar = A + ((size_t)b*SS+tid)*EE;
  float s=0.f;
  #pragma unroll
  for (int e=0;e<EE;e+=4){
    float4 a=*(const float4*)(Ar+e);
    float4 bb=*(const float4*)(bq+e);
    float4 vw=*(const float4*)(vv+e);
    s += vw.x*tanh_fast(a.x+bb.x)+vw.y*tanh_fast(a.y+bb.y)+vw.z*tanh_fast(a.z+bb.z)+vw.w*tanh_fast(a.w+bb.w);
  }
  softmax256(s, red, p);
  const float* V0 = V + (size_t)b*SS*D2;
  float o=0.f;
  for (int k=0;k<SS;k++) o += p[k]*V0[(size_t)k*D2+tid];
  aggout[((size_t)b*SS+q)*D12 + off + tid] = (unsigned short)bf16_rne(o);
}

// ---------------- bilinear attention (ptb), bf16 out ----------------
__global__ __launch_bounds__(256) void k_attn_bil(const float* __restrict__ Pb, const float* __restrict__ hq,
                          const float* __restrict__ V, unsigned short* __restrict__ aggout, int off){
  __shared__ __align__(16) float hqq[D2];
  __shared__ float p[SS]; __shared__ float red[SS];
  int q=blockIdx.x, b=blockIdx.y, tid=threadIdx.x;
  hqq[tid]=hq[((size_t)b*SS+q)*D2+tid];
  __syncthreads();
  const float* Pr = Pb + ((size_t)b*SS+tid)*D2;
  float s=0.f;
  #pragma unroll
  for (int d=0;d<D2;d+=4){
    float4 a=*(const float4*)(Pr+d);
    float4 hh=*(const float4*)(hqq+d);
    s += a.x*hh.x+a.y*hh.y+a.z*hh.z+a.w*hh.w;
  }
  softmax256(s, red, p);
  const float* V0 = V + (size_t)b*SS*D2;
  float o=0.f;
  for (int k=0;k<SS;k++) o += p[k]*V0[(size_t)k*D2+tid];
  aggout[((size_t)b*SS+q)*D12 + off + tid] = (unsigned short)bf16_rne(o);
}

// ------- fused ptd/pts: MFMA scores + tanh/v reduce + softmax + PV, bf16 out -------
__global__ __launch_bounds__(256, 2) void k_mulattn_fused(
    const unsigned short* __restrict__ keysb,
    const float* __restrict__ qm,
    const unsigned short* __restrict__ Wb,
    const float* __restrict__ v,
    const float* __restrict__ V,
    unsigned short* __restrict__ aggout, int off){
  __shared__ __align__(16) float qrow[D2];
  __shared__ __align__(16) float vrow[EE];
  __shared__ float scq[SS];
  __shared__ float red[SS];
  __shared__ float p[SS];
  int q=blockIdx.x, b=blockIdx.y, tid=threadIdx.x;
  int wave=tid>>6, lane=tid&63;
  size_t bS = (size_t)b*SS;
  qrow[tid]=qm[(bS+q)*D2+tid];
  if (tid<EE) vrow[tid]=v[tid];
  __syncthreads();

  f32x16 acc[2][4]={};
  int m0 = wave*64;
  int col = lane&31, half = lane>>5;
  const unsigned short* krow0 = keysb + (bS + m0 + col)*D2 + half*8;
  const unsigned short* krow1 = krow0 + 32*D2;
  const unsigned short* wrow[4];
  #pragma unroll
  for (int n=0;n<4;n++) wrow[n] = Wb + (size_t)(n*32+col)*D2 + half*8;

  for (int d0=0; d0<D2; d0+=16){
    float4 qsA = *(const float4*)&qrow[d0 + half*8];
    float4 qsB = *(const float4*)&qrow[d0 + half*8 + 4];
    short8 bfrag[4];
    #pragma unroll
    for (int n=0;n<4;n++) bfrag[n] = __builtin_bit_cast(short8, *(const uint4*)(wrow[n]+d0));
    #pragma unroll
    for (int i=0;i<2;i++){
      uint4 raw = *(const uint4*)((i? krow1:krow0) + d0);
      float f0=bf16_to_f(raw.x)*qsA.x, f1=bf16hi_to_f(raw.x)*qsA.y;
      float f2=bf16_to_f(raw.y)*qsA.z, f3=bf16hi_to_f(raw.y)*qsA.w;
      float f4=bf16_to_f(raw.z)*qsB.x, f5=bf16hi_to_f(raw.z)*qsB.y;
      float f6=bf16_to_f(raw.w)*qsB.z, f7=bf16hi_to_f(raw.w)*qsB.w;
      uint4 pk;
      pk.x=pack_bf16x2(f0,f1);
      pk.y=pack_bf16x2(f2,f3);
      pk.z=pack_bf16x2(f4,f5);
      pk.w=pack_bf16x2(f6,f7);
      short8 afrag = __builtin_bit_cast(short8, pk);
      #pragma unroll
      for (int n=0;n<4;n++)
        acc[i][n] = __builtin_amdgcn_mfma_f32_32x32x16_bf16(afrag, bfrag[n], acc[i][n], 0,0,0);
    }
  }
  float vn[4];
  #pragma unroll
  for (int n=0;n<4;n++) vn[n]=vrow[n*32+col];
  #pragma unroll
  for (int i=0;i<2;i++){
    #pragma unroll
    for (int r=0;r<16;r++){
      float s = vn[0]*tanh_fast(acc[i][0][r]) + vn[1]*tanh_fast(acc[i][1][r])
              + vn[2]*tanh_fast(acc[i][2][r]) + vn[3]*tanh_fast(acc[i][3][r]);
      s += __shfl_xor(s,1,32); s += __shfl_xor(s,2,32); s += __shfl_xor(s,4,32);
      s += __shfl_xor(s,8,32); s += __shfl_xor(s,16,32);
      int k = m0 + i*32 + (r&3) + 8*(r>>2) + 4*half;
      scq[k] = s;
    }
  }
  __syncthreads();
  float val = scq[tid];
  softmax256(val, red, p);
  const float* V0 = V + bS*D2;
  float o=0.f;
  for (int k=0;k<SS;k++) o += p[k]*V0[(size_t)k*D2+tid];
  aggout[(bS+q)*D12 + off + tid] = (unsigned short)bf16_rne(o);
}

// ---------------- rl pooling over hq + folded sB = rl @ Wc2^T ----------------
__global__ __launch_bounds__(256) void k_rl(const float* __restrict__ spj, const float* __restrict__ hq,
                    const float* __restrict__ vp, const float* __restrict__ Wc2,
                    float* __restrict__ sB){
  __shared__ __align__(16) float vpl[EE];
  __shared__ float p[SS]; __shared__ float red[SS];
  __shared__ __align__(16) float rr[D2];
  int b=blockIdx.x, tid=threadIdx.x;
  if (tid<EE) vpl[tid]=vp[tid];
  __syncthreads();
  const float* row = spj + ((size_t)b*SS+tid)*EE;
  float sj=0.f;
  #pragma unroll
  for (int e=0;e<EE;e+=4){
    float4 a=*(const float4*)(row+e);
    float4 vw=*(const float4*)(vpl+e);
    sj += vw.x*tanh_fast(a.x)+vw.y*tanh_fast(a.y)+vw.z*tanh_fast(a.z)+vw.w*tanh_fast(a.w);
  }
  softmax256(sj, red, p);
  float o=0.f;
  for (int s=0;s<SS;s++) o += p[s]*hq[((size_t)b*SS+s)*D2+tid];
  rr[tid]=o; __syncthreads();
  if (tid<EE){
    const float* wr = Wc2 + (size_t)tid*D2;
    float a=0.f;
    #pragma unroll
    for (int d=0;d<D2;d+=4){
      float4 w4=*(const float4*)(wr+d);
      float4 r4=*(const float4*)(rr+d);
      a += w4.x*r4.x+w4.y*r4.y+w4.z*r4.z+w4.w*r4.w;
    }
    sB[(size_t)b*EE+tid]=a;
  }
}

// ---------------- final pooling + prediction ----------------
__global__ __launch_bounds__(256) void k_final(const float* __restrict__ sA, const float* __restrict__ sB,
                       const float* __restrict__ vc, const float* __restrict__ agg_rep,
                       const float* __restrict__ Wpred, float* __restrict__ out){
  __shared__ __align__(16) float sBl[EE];
  __shared__ __align__(16) float vcl[EE];
  __shared__ float p[SS]; __shared__ float red[SS]; __shared__ float rr[D2];
  int b=blockIdx.x, tid=threadIdx.x;
  if (tid<EE){ sBl[tid]=sB[(size_t)b*EE+tid]; vcl[tid]=vc[tid]; }
  __syncthreads();
  const float* rowA = sA + ((size_t)b*SS+tid)*EE;
  float sc=0.f;
  #pragma unroll
  for (int e=0;e<EE;e+=4){
    float4 a=*(const float4*)(rowA+e);
    float4 bb=*(const float4*)(sBl+e);
    float4 vw=*(const float4*)(vcl+e);
    sc += vw.x*(a.x+bb.x)+vw.y*(a.y+bb.y)+vw.z*(a.z+bb.z)+vw.w*(a.w+bb.w);
  }
  softmax256(sc, red, p);
  float o=0.f;
  for (int s=0;s<SS;s++) o += p[s]*agg_rep[((size_t)b*SS+s)*D2+tid];
  rr[tid]=o; __syncthreads();
  if (tid<LL){
    float a=0.f;
    const float* wr = Wpred + (size_t)tid*D2;
    for (int d=0;d<D2;d++) a += wr[d]*rr[d];
    out[(size_t)b*LL+tid]=sigmoidf_(a);
  }
}

extern "C" void kernel_launch(void* const* d_in, const int* in_sizes, int n_in,
                              void* d_out, int out_size, void* d_ws, size_t ws_size,
                              hipStream_t stream){
  (void)in_sizes; (void)n_in; (void)out_size; (void)ws_size;
  const int*   inp = (const int*)d_in[0];
  const float* emb = (const float*)d_in[1];
  const float* enc_wih_f=(const float*)d_in[2],  *enc_whh_f=(const float*)d_in[3],
             *enc_bih_f=(const float*)d_in[4],  *enc_bhh_f=(const float*)d_in[5];
  const float* enc_wih_b=(const float*)d_in[6],  *enc_whh_b=(const float*)d_in[7],
             *enc_bih_b=(const float*)d_in[8],  *enc_bhh_b=(const float*)d_in[9];
  const float* hid_wih_f=(const float*)d_in[10], *hid_whh_f=(const float*)d_in[11],
             *hid_bih_f=(const float*)d_in[12], *hid_bhh_f=(const float*)d_in[13];
  const float* hid_wih_b=(const float*)d_in[14], *hid_whh_b=(const float*)d_in[15],
             *hid_bih_b=(const float*)d_in[16], *hid_bhh_b=(const float*)d_in[17];
  const float* agg_wih_f=(const float*)d_in[18], *agg_whh_f=(const float*)d_in[19],
             *agg_bih_f=(const float*)d_in[20], *agg_bhh_f=(const float*)d_in[21];
  const float* agg_wih_b=(const float*)d_in[22], *agg_whh_b=(const float*)d_in[23],
             *agg_bih_b=(const float*)d_in[24], *agg_bhh_b=(const float*)d_in[25];
  const float* Wc1=(const float*)d_in[26], *Wc2=(const float*)d_in[27], *vc=(const float*)d_in[28];
  const float* Wb =(const float*)d_in[29];
  const float* Wd =(const float*)d_in[30], *vd=(const float*)d_in[31];
  const float* Wm =(const float*)d_in[32], *vm=(const float*)d_in[33];
  const float* Ws =(const float*)d_in[34], *vs=(const float*)d_in[35];
  const float* Wp =(const float*)d_in[36], *vp=(const float*)d_in[37];
  const float* Wpred=(const float*)d_in[38];

  float* ws = (float*)d_ws;
  size_t o = 0;
  float* gxf     = ws + o; o += (size_t)BB*SS*H3;
  float* gxb     = ws + o; o += (size_t)BB*SS*H3;
  float* hp      = ws + o; o += (size_t)BB*SS*D2;
  float* hq      = ws + o; o += (size_t)BB*SS*D2;
  float* hidden  = ws + o; o += (size_t)2*BB*EE;
  float* s1      = ws + o; o += (size_t)BB*SS*EE;
  float* s2      = ws + o; o += (size_t)BB*SS*EE;
  float* Am      = ws + o; o += (size_t)BB*SS*EE;
  float* Bm      = ws + o; o += (size_t)BB*SS*EE;
  float* Pb      = ws + o; o += (size_t)BB*SS*D2;
  float* spj     = ws + o; o += (size_t)BB*SS*EE;
  float* agg_rep = ws + o; o += (size_t)BB*SS*D2;
  float* sA      = ws + o; o += (size_t)BB*SS*EE;
  float* sB      = ws + o; o += (size_t)BB*EE;
  // bf16 buffers (ushort counts, all even -> advance o by count/2)
  unsigned short* x_bf      = (unsigned short*)(ws+o); o += (size_t)BB*SS*DP/2;
  unsigned short* hp_bf     = (unsigned short*)(ws+o); o += (size_t)BB*SS*D2/2;
  unsigned short* hq_bf     = (unsigned short*)(ws+o); o += (size_t)BB*SS*D2/2;
  unsigned short* agg_bf    = (unsigned short*)(ws+o); o += (size_t)BB*SS*D12/2;
  unsigned short* aggrep_bf = (unsigned short*)(ws+o); o += (size_t)BB*SS*D2/2;
  unsigned short* encf_bf   = (unsigned short*)(ws+o); o += (size_t)H3*DP/2;
  unsigned short* encb_bf   = (unsigned short*)(ws+o); o += (size_t)H3*DP/2;
  unsigned short* hidf_bf   = (unsigned short*)(ws+o); o += (size_t)H3*D2/2;
  unsigned short* hidb_bf   = (unsigned short*)(ws+o); o += (size_t)H3*D2/2;
  unsigned short* aggf_bf   = (unsigned short*)(ws+o); o += (size_t)H3*D12/2;
  unsigned short* aggb_bf   = (unsigned short*)(ws+o); o += (size_t)H3*D12/2;
  unsigned short* Wc1_bf    = (unsigned short*)(ws+o); o += (size_t)EE*D2/2;
  unsigned short* Wc2_bf    = (unsigned short*)(ws+o); o += (size_t)EE*D2/2;
  unsigned short* Wm_bf     = (unsigned short*)(ws+o); o += (size_t)EE*D2/2;
  unsigned short* Wb_bf     = (unsigned short*)(ws+o); o += (size_t)D2*D2/2;
  unsigned short* Wp_bf     = (unsigned short*)(ws+o); o += (size_t)EE*D2/2;
  unsigned short* Wd_bf     = (unsigned short*)(ws+o); o += (size_t)EE*D2/2;
  unsigned short* Ws_bf     = (unsigned short*)(ws+o); o += (size_t)EE*D2/2;

  const int M = BB*SS; // 1024
  auto mmbf=[&](const unsigned short* X,const unsigned short* W,const float* bias,
                float* outp,int N,int K,int z,int kspan){
    dim3 g(N/32, M/64, z);
    k_mmbf<<<g,64,0,stream>>>(X,W,bias,outp,N,K,kspan);
  };

  // ---- input prep ----
  k_embed<<<M,256,0,stream>>>(inp, emb, x_bf);
  CvtArgs ca;
  ca.s[0]  = {enc_wih_f, encf_bf, H3, DD, DP};
  ca.s[1]  = {enc_wih_b, encb_bf, H3, DD, DP};
  ca.s[2]  = {hid_wih_f, hidf_bf, H3, D2, D2};
  ca.s[3]  = {hid_wih_b, hidb_bf, H3, D2, D2};
  ca.s[4]  = {agg_wih_f, aggf_bf, H3, D12, D12};
  ca.s[5]  = {agg_wih_b, aggb_bf, H3, D12, D12};
  ca.s[6]  = {Wc1, Wc1_bf, EE, D2, D2};
  ca.s[7]  = {Wc2, Wc2_bf, EE, D2, D2};
  ca.s[8]  = {Wm,  Wm_bf,  EE, D2, D2};
  ca.s[9]  = {Wb,  Wb_bf,  D2, D2, D2};
  ca.s[10] = {Wp,  Wp_bf,  EE, D2, D2};
  ca.s[11] = {Wd,  Wd_bf,  EE, D2, D2};
  ca.s[12] = {Ws,  Ws_bf,  EE, D2, D2};
  {
    int maxpairs = H3*D12/2;  // 294912
    dim3 g((maxpairs+255)/256, 13);
    k_cvt_weights<<<g,256,0,stream>>>(ca);
  }

  // ---- encoder BiGRU ----
  k_init2<<<M,H3,0,stream>>>(gxf, enc_bih_f, gxb, enc_bih_b);
  mmbf(x_bf, encf_bf, nullptr, gxf, H3, DP, 4, 80);
  mmbf(x_bf, encb_bf, nullptr, gxb, H3, DP, 4, 80);
  k_gru_scan<<<dim3(2),256,0,stream>>>(gxf,gxb,enc_whh_f,enc_whh_b,enc_bhh_f,enc_bhh_b,
                                       nullptr,hp,hidden);
  k_cvt_bf16<<<(M*D2/2+255)/256,256,0,stream>>>(hp, hp_bf, M*D2/2);

  // ---- hidden BiGRU ----
  k_init2<<<M,H3,0,stream>>>(gxf, hid_bih_f, gxb, hid_bih_b);
  mmbf(hp_bf, hidf_bf, nullptr, gxf, H3, D2, 4, 64);
  mmbf(hp_bf, hidb_bf, nullptr, gxb, H3, D2, 4, 64);
  k_gru_scan<<<dim3(2),256,0,stream>>>(gxf,gxb,hid_whh_f,hid_whh_b,hid_bhh_f,hid_bhh_b,
                                       hidden,hq,nullptr);
  k_cvt_bf16<<<(M*D2/2+255)/256,256,0,stream>>>(hq, hq_bf, M*D2/2);

  // ---- projections (ksplit=1, direct store) ----
  mmbf(hp_bf, Wc1_bf, nullptr, s1,  EE, D2, 1, D2);
  mmbf(hq_bf, Wc2_bf, nullptr, s2,  EE, D2, 1, D2);
  mmbf(hp_bf, Wm_bf,  nullptr, Am,  EE, D2, 1, D2);
  mmbf(hq_bf, Wm_bf,  nullptr, Bm,  EE, D2, 1, D2);
  mmbf(hp_bf, Wb_bf,  nullptr, Pb,  D2, D2, 1, D2);
  mmbf(hq_bf, Wp_bf,  nullptr, spj, EE, D2, 1, D2);

  // ---- attentions -> agg (bf16). slices: hq(0) pts(256) ptc(512) ptd(768) ptb(1024) ptm(1280)
  k_copy_hq<<<M,256,0,stream>>>(hq_bf, agg_bf);
  dim3 gq(SS,BB);
  k_attn_add<<<gq,256,0,stream>>>(s1,s2,vc, 1.f, hp, agg_bf, 512);
  k_attn_add<<<gq,256,0,stream>>>(Am,Bm,vm,-1.f, hp, agg_bf, 1280);
  k_attn_bil<<<gq,256,0,stream>>>(Pb,hq,hp,agg_bf,1024);
  k_mulattn_fused<<<gq,256,0,stream>>>(hp_bf,hq,Wd_bf,vd,hp,agg_bf,768);
  k_mulattn_fused<<<gq,256,0,stream>>>(hq_bf,hq,Ws_bf,vs,hq,agg_bf,256);

  // ---- aggregation BiGRU ----
  k_init2<<<M,H3,0,stream>>>(gxf, agg_bih_f, gxb, agg_bih_b);
  mmbf(agg_bf, aggf_bf, nullptr, gxf, H3, D12, 8, 192);
  mmbf(agg_bf, aggb_bf, nullptr, gxb, H3, D12, 8, 192);
  k_gru_scan<<<dim3(2),256,0,stream>>>(gxf,gxb,agg_whh_f,agg_whh_b,agg_bhh_f,agg_bhh_b,
                                       nullptr,agg_rep,nullptr);
  k_cvt_bf16<<<(M*D2/2+255)/256,256,0,stream>>>(agg_rep, aggrep_bf, M*D2/2);

  // ---- pooling + prediction ----
  k_rl<<<BB,256,0,stream>>>(spj,hq,vp,Wc2,sB);
  mmbf(aggrep_bf, Wc1_bf, nullptr, sA, EE, D2, 1, D2);
  k_final<<<BB,256,0,stream>>>(sA,sB,vc,agg_rep,Wpred,(float*)d_out);
}

// Round 4
// 1648.031 us; speedup vs baseline: 1.1971x; 1.1971x over previous
//
#include <hip/hip_runtime.h>
#include <math.h>

#define BB 4
#define SS 256
#define DD 300
#define DP 304   // DD padded to multiple of 16
#define EE 128
#define LL 20
#define H3 384
#define D2 256   // 2E
#define D12 1536 // 12E

typedef __attribute__((ext_vector_type(8)))  short short8;
typedef __attribute__((ext_vector_type(16))) float f32x16;
typedef __attribute__((ext_vector_type(4)))  float f32x4;
typedef __attribute__((ext_vector_type(4)))  unsigned int u32x4;

__device__ __forceinline__ float tanh_fast(float x){
  float e = __expf(2.f*x);
  return 1.f - 2.f/(e+1.f);
}
__device__ __forceinline__ float sigmoidf_(float x){ return 1.f/(1.f+__expf(-x)); }
__device__ __forceinline__ float bf16_to_f(unsigned u){ return __builtin_bit_cast(float, u<<16); }
__device__ __forceinline__ float bf16hi_to_f(unsigned u){ return __builtin_bit_cast(float, u & 0xFFFF0000u); }
__device__ __forceinline__ unsigned bf16_rne(float f){
  unsigned u = __builtin_bit_cast(unsigned, f);
  return (u + 0x7FFFu + ((u>>16)&1u)) >> 16;
}
__device__ __forceinline__ unsigned pack_bf16x2(float lo, float hi){
  return bf16_rne(lo) | (bf16_rne(hi)<<16);
}

// ---------------- f32 -> bf16 (RNE), 2 elems/thread ----------------
__global__ void k_cvt_bf16(const float* __restrict__ src, unsigned short* __restrict__ dst, int n2){
  int i = blockIdx.x*blockDim.x + threadIdx.x;
  if (i < n2){
    float2 f = *(const float2*)(src + 2*i);
    *(unsigned*)(dst + 2*i) = pack_bf16x2(f.x, f.y);
  }
}

// ---------------- fused weight conversion (13 segments, K-padding aware) ----------------
struct CvtSeg { const float* src; unsigned short* dst; int rows, Ks, Kd; };
struct CvtArgs { CvtSeg s[13]; };
__global__ void k_cvt_weights(CvtArgs a){
  CvtSeg sg = a.s[blockIdx.y];
  int p = blockIdx.x*256 + threadIdx.x;          // dst pair index
  int Kd2 = sg.Kd>>1;
  int npairs = sg.rows*Kd2;
  if (p >= npairs) return;
  int row = p/Kd2, kk = (p - row*Kd2)*2;
  float f0 = (kk   < sg.Ks)? sg.src[(size_t)row*sg.Ks+kk  ] : 0.f;
  float f1 = (kk+1 < sg.Ks)? sg.src[(size_t)row*sg.Ks+kk+1] : 0.f;
  *(unsigned*)(sg.dst + (size_t)row*sg.Kd + kk) = pack_bf16x2(f0,f1);
}

// ---------------- embedding gather -> padded bf16 ----------------
__global__ void k_embed(const int* __restrict__ inp, const float* __restrict__ emb,
                        unsigned short* __restrict__ xb){
  int row = blockIdx.x;            // b*S+s
  int idx = inp[row];
  const float* src = emb + (size_t)idx*DD;
  unsigned short* dst = xb + (size_t)row*DP;
  int p = threadIdx.x;             // pair index, 152 pairs
  if (p < DP/2){
    float f0 = (2*p   < DD)? src[2*p  ] : 0.f;
    float f1 = (2*p+1 < DD)? src[2*p+1] : 0.f;
    *(unsigned*)(dst + 2*p) = pack_bf16x2(f0,f1);
  }
}

// ---------------- init gx pair with input-projection biases ----------------
__global__ void k_init2(float* __restrict__ gf, const float* __restrict__ bf,
                        float* __restrict__ gb, const float* __restrict__ bb){
  int row = blockIdx.x, n = threadIdx.x;   // block = H3 threads
  gf[(size_t)row*H3+n] = bf[n];
  gb[(size_t)row*H3+n] = bb[n];
}

// ---------------- bf16 MFMA matmul: out[M,N] (+)= X[M,K] @ W[N,K]^T ----------------
__global__ __launch_bounds__(64) void k_mmbf(
    const unsigned short* __restrict__ X, const unsigned short* __restrict__ W,
    const float* __restrict__ bias, float* __restrict__ out,
    int N, int K, int kspan){
  int lane=threadIdx.x, col=lane&31, half=lane>>5;
  int n0=blockIdx.x*32, m0=blockIdx.y*64;
  int ks=blockIdx.z*kspan, ke=ks+kspan; if (ke>K) ke=K;
  const unsigned short* pa0 = X + (size_t)(m0+col)*K + half*8;
  const unsigned short* pa1 = pa0 + (size_t)32*K;
  const unsigned short* pb  = W + (size_t)(n0+col)*K + half*8;
  f32x16 acc0={}, acc1={};
  #pragma unroll 2
  for (int k=ks;k<ke;k+=16){
    short8 a0=__builtin_bit_cast(short8, *(const uint4*)(pa0+k));
    short8 a1=__builtin_bit_cast(short8, *(const uint4*)(pa1+k));
    short8 bv=__builtin_bit_cast(short8, *(const uint4*)(pb +k));
    acc0=__builtin_amdgcn_mfma_f32_32x32x16_bf16(a0,bv,acc0,0,0,0);
    acc1=__builtin_amdgcn_mfma_f32_32x32x16_bf16(a1,bv,acc1,0,0,0);
  }
  int cn = n0+col;
  if (gridDim.z==1){
    float bn = bias? bias[cn] : 0.f;
    #pragma unroll
    for (int r=0;r<16;r++){
      int row=(r&3)+8*(r>>2)+4*half;
      out[(size_t)(m0+row)*N+cn]    = acc0[r]+bn;
      out[(size_t)(m0+32+row)*N+cn] = acc1[r]+bn;
    }
  } else {
    #pragma unroll
    for (int r=0;r<16;r++){
      int row=(r&3)+8*(r>>2)+4*half;
      atomicAdd(&out[(size_t)(m0+row)*N+cn],    acc0[r]);
      atomicAdd(&out[(size_t)(m0+32+row)*N+cn], acc1[r]);
    }
  }
}

// ---------------- GRU scan: MFMA recurrence, latency-optimized ----------------
// One block per direction, 512 threads = 8 waves. Wave w owns h-rows
// [16w,16w+16) -> weight tiles {w, w+8, w+16} (r/z/n gates), 12 MFMA/step
// in 2-deep chains. Operands SWAPPED vs round 3: scores = W_tile @ h^T
// (A=weights, B=h^T), so C has col=batch, row=output-row: each active lane
// (lane&15 < 4) owns the full r/z/n gate triple for 4 CONSECUTIVE rows of
// ONE batch -> gx/bias/h/out are all float4 ops, no cross-lane traffic.
// gx for step t+1 is prefetched during step t (global latency off the
// critical path). h round-trips through the conflict-free 68-word-stride
// LDS fragment buffer (identical layout to round 3, 1 ds_write_b64/lane).
__global__ __launch_bounds__(512, 1) void k_gru_scan(
                          const float* __restrict__ gxf, const float* __restrict__ gxb,
                          const float* __restrict__ whhf, const float* __restrict__ whhb,
                          const float* __restrict__ bhhf, const float* __restrict__ bhhb,
                          const float* __restrict__ h0,
                          float* __restrict__ out,
                          float* __restrict__ hT){
  int dir = blockIdx.x, tid = threadIdx.x;
  const float* gx  = dir? gxb : gxf;
  const float* whh = dir? whhb : whhf;
  const float* bhh = dir? bhhb : bhhf;
  int w = tid>>6, lane = tid&63;
  int q = lane>>4, c = lane&15;          // k-quarter, col-in-tile
  bool act = (c < BB);                   // active lanes own (batch=c, 4 rows)
  int b = c;
  int rbase = w*16 + 4*q;                // first of this lane's 4 rows

  // ---- A fragments: weights, 3 tiles x 4 k-tiles, register-resident ----
  short8 wfr[3][4];
  {
    const int tiles[3] = {w, w+8, w+16};
    #pragma unroll
    for (int ti=0; ti<3; ti++){
      const float* wr = whh + (size_t)(tiles[ti]*16 + c)*EE + q*8;
      #pragma unroll
      for (int kt=0; kt<4; kt++){
        float4 f0 = *(const float4*)(wr + kt*32);
        float4 f1 = *(const float4*)(wr + kt*32 + 4);
        u32x4 pk;
        pk.x = pack_bf16x2(f0.x, f0.y); pk.y = pack_bf16x2(f0.z, f0.w);
        pk.z = pack_bf16x2(f1.x, f1.y); pk.w = pack_bf16x2(f1.z, f1.w);
        asm volatile("" : "+v"(pk));   // opaque: no remat, stays in VGPRs
        wfr[ti][kt] = __builtin_bit_cast(short8, pk);
      }
    }
  }

  // h buffer: [2][group 16][68 words]; group g=k>>3 holds 8 k-values as
  // 4 bf16-pair words per batch: word = b*4 + (k&7)>>1. Reader (B-frag):
  // lane l reads words (kt*4 + (l>>4))*68 + (l&15)*4 .. +3  (b128, ~no conflicts)
  __shared__ float hbuf[2*1088];
  for (int i=tid; i<2*1088; i+=512) hbuf[i] = 0.f;

  f32x4 br={}, bz={}, bn={}, hp={};
  if (act){
    br = *(const f32x4*)&bhh[rbase];
    bz = *(const f32x4*)&bhh[EE + rbase];
    bn = *(const f32x4*)&bhh[2*EE + rbase];
    if (h0) hp = *(const f32x4*)&h0[((size_t)dir*BB+b)*EE + rbase];
  }
  int g = 2*w + (q>>1);
  int wword = g*68 + b*4 + (q&1)*2;      // this lane's 2-dword slot
  __syncthreads();                       // zero-init done before packing
  if (act){
    unsigned u0 = pack_bf16x2(hp[0], hp[1]);
    unsigned u1 = pack_bf16x2(hp[2], hp[3]);
    *(uint2*)&hbuf[wword] = make_uint2(u0, u1);
  }
  // gx for step 0
  f32x4 ga0={},ga1={},ga2={},gb0={},gb1={},gb2={};
  if (act){
    int s0 = dir? (SS-1) : 0;
    const float* gp = gx + ((size_t)b*SS+s0)*H3 + rbase;
    ga0 = *(const f32x4*)(gp);
    ga1 = *(const f32x4*)(gp + EE);
    ga2 = *(const f32x4*)(gp + 2*EE);
  }
  __syncthreads();

  auto step = [&](int t, f32x4& gc0, f32x4& gc1, f32x4& gc2,
                         f32x4& gn0, f32x4& gn1, f32x4& gn2){
    int s = dir? (SS-1-t) : t;
    // prefetch gx for t+1 (covered by this step's MFMA+gates+barrier)
    if (t+1 < SS && act){
      int s1 = dir? (SS-2-t) : (t+1);
      const float* gp = gx + ((size_t)b*SS+s1)*H3 + rbase;
      gn0 = *(const f32x4*)(gp);
      gn1 = *(const f32x4*)(gp + EE);
      gn2 = *(const f32x4*)(gp + 2*EE);
    }
    // B fragments: current h
    const float* hb = &hbuf[(t&1)*1088];
    short8 hfr[4];
    #pragma unroll
    for (int kt=0; kt<4; kt++)
      hfr[kt] = __builtin_bit_cast(short8, *(const u32x4*)&hb[(kt*4+q)*68 + c*4]);
    // 12 MFMA, 6 independent 2-deep chains
    f32x4 aR0={},aZ0={},aN0={},aR1={},aZ1={},aN1={};
    aR0 = __builtin_amdgcn_mfma_f32_16x16x32_bf16(wfr[0][0], hfr[0], aR0,0,0,0);
    aZ0 = __builtin_amdgcn_mfma_f32_16x16x32_bf16(wfr[1][0], hfr[0], aZ0,0,0,0);
    aN0 = __builtin_amdgcn_mfma_f32_16x16x32_bf16(wfr[2][0], hfr[0], aN0,0,0,0);
    aR1 = __builtin_amdgcn_mfma_f32_16x16x32_bf16(wfr[0][2], hfr[2], aR1,0,0,0);
    aZ1 = __builtin_amdgcn_mfma_f32_16x16x32_bf16(wfr[1][2], hfr[2], aZ1,0,0,0);
    aN1 = __builtin_amdgcn_mfma_f32_16x16x32_bf16(wfr[2][2], hfr[2], aN1,0,0,0);
    aR0 = __builtin_amdgcn_mfma_f32_16x16x32_bf16(wfr[0][1], hfr[1], aR0,0,0,0);
    aZ0 = __builtin_amdgcn_mfma_f32_16x16x32_bf16(wfr[1][1], hfr[1], aZ0,0,0,0);
    aN0 = __builtin_amdgcn_mfma_f32_16x16x32_bf16(wfr[2][1], hfr[1], aN0,0,0,0);
    aR1 = __builtin_amdgcn_mfma_f32_16x16x32_bf16(wfr[0][3], hfr[3], aR1,0,0,0);
    aZ1 = __builtin_amdgcn_mfma_f32_16x16x32_bf16(wfr[1][3], hfr[3], aZ1,0,0,0);
    aN1 = __builtin_amdgcn_mfma_f32_16x16x32_bf16(wfr[2][3], hfr[3], aN1,0,0,0);
    f32x4 aR = aR0+aR1, aZ = aZ0+aZ1, aN = aN0+aN1;
    // gates: 4 rows x 1 batch per active lane, all in-register
    if (act){
      f32x4 h2;
      #pragma unroll
      for (int i=0;i<4;i++){
        float rg = sigmoidf_(gc0[i] + aR[i] + br[i]);
        float zg = sigmoidf_(gc1[i] + aZ[i] + bz[i]);
        float ng = tanh_fast (gc2[i] + rg*(aN[i] + bn[i]));
        h2[i] = (1.f-zg)*ng + zg*hp[i];
      }
      hp = h2;
      *(f32x4*)&out[((size_t)b*SS+s)*D2 + (size_t)dir*EE + rbase] = h2;
      unsigned u0 = pack_bf16x2(h2[0], h2[1]);
      unsigned u1 = pack_bf16x2(h2[2], h2[3]);
      *(uint2*)&hbuf[((t+1)&1)*1088 + wword] = make_uint2(u0, u1);
    }
    __syncthreads();
  };

  for (int t=0; t<SS; t+=2){
    step(t,   ga0,ga1,ga2, gb0,gb1,gb2);
    step(t+1, gb0,gb1,gb2, ga0,ga1,ga2);
  }
  if (hT && act) *(f32x4*)&hT[((size_t)dir*BB+b)*EE + rbase] = hp;
}

__global__ void k_copy_hq(const unsigned short* __restrict__ hqb, unsigned short* __restrict__ aggb){
  int row=blockIdx.x;
  aggb[(size_t)row*D12 + threadIdx.x] = hqb[(size_t)row*D2 + threadIdx.x];
}

// --------- block softmax over 256 values ---------
__device__ __forceinline__ void softmax256(float val, float* red, float* p){
  int tid=threadIdx.x;
  red[tid]=val; __syncthreads();
  for (int st=128; st>0; st>>=1){ if (tid<st) red[tid]=fmaxf(red[tid],red[tid+st]); __syncthreads(); }
  float mx=red[0]; __syncthreads();
  float ex=__expf(val-mx); red[tid]=ex; __syncthreads();
  for (int st=128; st>0; st>>=1){ if (tid<st) red[tid]+=red[tid+st]; __syncthreads(); }
  float inv=1.f/red[0];
  p[tid]=ex*inv; __syncthreads();
}

// ---------------- additive-style attention (ptc: +1, ptm: -1), bf16 out ----------------
__global__ __launch_bounds__(256) void k_attn_add(const float* __restrict__ A, const float* __restrict__ Bq,
                          const float* __restrict__ v, float sign,
                          const float* __restrict__ V, unsigned short* __restrict__ aggout, int off){
  __shared__ __align__(16) float bq[EE];
  __shared__ __align__(16) float vv[EE];
  __shared__ float p[SS]; __shared__ float red[SS];
  int q=blockIdx.x, b=blockIdx.y, tid=threadIdx.x;
  if (tid<EE){ bq[tid]=sign*Bq[((size_t)b*SS+q)*EE+tid]; vv[tid]=v[tid]; }
  __syncthreads();
  const float* Ar = A + ((size_t)b*SS+tid)*EE;
  float s=0.f;
  #pragma unroll
  for (int e=0;e<EE;e+=4){
    float4 a=*(const float4*)(Ar+e);
    float4 bb=*(const float4*)(bq+e);
    float4 vw=*(const float4*)(vv+e);
    s += vw.x*tanh_fast(a.x+bb.x)+vw.y*tanh_fast(a.y+bb.y)+vw.z*tanh_fast(a.z+bb.z)+vw.w*tanh_fast(a.w+bb.w);
  }
  softmax256(s, red, p);
  const float* V0 = V + (size_t)b*SS*D2;
  float o=0.f;
  for (int k=0;k<SS;k++) o += p[k]*V0[(size_t)k*D2+tid];
  aggout[((size_t)b*SS+q)*D12 + off + tid] = (unsigned short)bf16_rne(o);
}

// ---------------- bilinear attention (ptb), bf16 out ----------------
__global__ __launch_bounds__(256) void k_attn_bil(const float* __restrict__ Pb, const float* __restrict__ hq,
                          const float* __restrict__ V, unsigned short* __restrict__ aggout, int off){
  __shared__ __align__(16) float hqq[D2];
  __shared__ float p[SS]; __shared__ float red[SS];
  int q=blockIdx.x, b=blockIdx.y, tid=threadIdx.x;
  hqq[tid]=hq[((size_t)b*SS+q)*D2+tid];
  __syncthreads();
  const float* Pr = Pb + ((size_t)b*SS+tid)*D2;
  float s=0.f;
  #pragma unroll
  for (int d=0;d<D2;d+=4){
    float4 a=*(const float4*)(Pr+d);
    float4 hh=*(const float4*)(hqq+d);
    s += a.x*hh.x+a.y*hh.y+a.z*hh.z+a.w*hh.w;
  }
  softmax256(s, red, p);
  const float* V0 = V + (size_t)b*SS*D2;
  float o=0.f;
  for (int k=0;k<SS;k++) o += p[k]*V0[(size_t)k*D2+tid];
  aggout[((size_t)b*SS+q)*D12 + off + tid] = (unsigned short)bf16_rne(o);
}

// ------- fused ptd/pts: MFMA scores + tanh/v reduce + softmax + PV, bf16 out -------
__global__ __launch_bounds__(256, 2) void k_mulattn_fused(
    const unsigned short* __restrict__ keysb,
    const float* __restrict__ qm,
    const unsigned short* __restrict__ Wb,
    const float* __restrict__ v,
    const float* __restrict__ V,
    unsigned short* __restrict__ aggout, int off){
  __shared__ __align__(16) float qrow[D2];
  __shared__ __align__(16) float vrow[EE];
  __shared__ float scq[SS];
  __shared__ float red[SS];
  __shared__ float p[SS];
  int q=blockIdx.x, b=blockIdx.y, tid=threadIdx.x;
  int wave=tid>>6, lane=tid&63;
  size_t bS = (size_t)b*SS;
  qrow[tid]=qm[(bS+q)*D2+tid];
  if (tid<EE) vrow[tid]=v[tid];
  __syncthreads();

  f32x16 acc[2][4]={};
  int m0 = wave*64;
  int col = lane&31, half = lane>>5;
  const unsigned short* krow0 = keysb + (bS + m0 + col)*D2 + half*8;
  const unsigned short* krow1 = krow0 + 32*D2;
  const unsigned short* wrow[4];
  #pragma unroll
  for (int n=0;n<4;n++) wrow[n] = Wb + (size_t)(n*32+col)*D2 + half*8;

  for (int d0=0; d0<D2; d0+=16){
    float4 qsA = *(const float4*)&qrow[d0 + half*8];
    float4 qsB = *(const float4*)&qrow[d0 + half*8 + 4];
    short8 bfrag[4];
    #pragma unroll
    for (int n=0;n<4;n++) bfrag[n] = __builtin_bit_cast(short8, *(const uint4*)(wrow[n]+d0));
    #pragma unroll
    for (int i=0;i<2;i++){
      uint4 raw = *(const uint4*)((i? krow1:krow0) + d0);
      float f0=bf16_to_f(raw.x)*qsA.x, f1=bf16hi_to_f(raw.x)*qsA.y;
      float f2=bf16_to_f(raw.y)*qsA.z, f3=bf16hi_to_f(raw.y)*qsA.w;
      float f4=bf16_to_f(raw.z)*qsB.x, f5=bf16hi_to_f(raw.z)*qsB.y;
      float f6=bf16_to_f(raw.w)*qsB.z, f7=bf16hi_to_f(raw.w)*qsB.w;
      uint4 pk;
      pk.x=pack_bf16x2(f0,f1);
      pk.y=pack_bf16x2(f2,f3);
      pk.z=pack_bf16x2(f4,f5);
      pk.w=pack_bf16x2(f6,f7);
      short8 afrag = __builtin_bit_cast(short8, pk);
      #pragma unroll
      for (int n=0;n<4;n++)
        acc[i][n] = __builtin_amdgcn_mfma_f32_32x32x16_bf16(afrag, bfrag[n], acc[i][n], 0,0,0);
    }
  }
  float vn[4];
  #pragma unroll
  for (int n=0;n<4;n++) vn[n]=vrow[n*32+col];
  #pragma unroll
  for (int i=0;i<2;i++){
    #pragma unroll
    for (int r=0;r<16;r++){
      float s = vn[0]*tanh_fast(acc[i][0][r]) + vn[1]*tanh_fast(acc[i][1][r])
              + vn[2]*tanh_fast(acc[i][2][r]) + vn[3]*tanh_fast(acc[i][3][r]);
      s += __shfl_xor(s,1,32); s += __shfl_xor(s,2,32); s += __shfl_xor(s,4,32);
      s += __shfl_xor(s,8,32); s += __shfl_xor(s,16,32);
      int k = m0 + i*32 + (r&3) + 8*(r>>2) + 4*half;
      scq[k] = s;
    }
  }
  __syncthreads();
  float val = scq[tid];
  softmax256(val, red, p);
  const float* V0 = V + bS*D2;
  float o=0.f;
  for (int k=0;k<SS;k++) o += p[k]*V0[(size_t)k*D2+tid];
  aggout[(bS+q)*D12 + off + tid] = (unsigned short)bf16_rne(o);
}

// ---------------- rl pooling over hq + folded sB = rl @ Wc2^T ----------------
__global__ __launch_bounds__(256) void k_rl(const float* __restrict__ spj, const float* __restrict__ hq,
                    const float* __restrict__ vp, const float* __restrict__ Wc2,
                    float* __restrict__ sB){
  __shared__ __align__(16) float vpl[EE];
  __shared__ float p[SS]; __shared__ float red[SS];
  __shared__ __align__(16) float rr[D2];
  int b=blockIdx.x, tid=threadIdx.x;
  if (tid<EE) vpl[tid]=vp[tid];
  __syncthreads();
  const float* row = spj + ((size_t)b*SS+tid)*EE;
  float sj=0.f;
  #pragma unroll
  for (int e=0;e<EE;e+=4){
    float4 a=*(const float4*)(row+e);
    float4 vw=*(const float4*)(vpl+e);
    sj += vw.x*tanh_fast(a.x)+vw.y*tanh_fast(a.y)+vw.z*tanh_fast(a.z)+vw.w*tanh_fast(a.w);
  }
  softmax256(sj, red, p);
  float o=0.f;
  for (int s=0;s<SS;s++) o += p[s]*hq[((size_t)b*SS+s)*D2+tid];
  rr[tid]=o; __syncthreads();
  if (tid<EE){
    const float* wr = Wc2 + (size_t)tid*D2;
    float a=0.f;
    #pragma unroll
    for (int d=0;d<D2;d+=4){
      float4 w4=*(const float4*)(wr+d);
      float4 r4=*(const float4*)(rr+d);
      a += w4.x*r4.x+w4.y*r4.y+w4.z*r4.z+w4.w*r4.w;
    }
    sB[(size_t)b*EE+tid]=a;
  }
}

// ---------------- final pooling + prediction ----------------
__global__ __launch_bounds__(256) void k_final(const float* __restrict__ sA, const float* __restrict__ sB,
                       const float* __restrict__ vc, const float* __restrict__ agg_rep,
                       const float* __restrict__ Wpred, float* __restrict__ out){
  __shared__ __align__(16) float sBl[EE];
  __shared__ __align__(16) float vcl[EE];
  __shared__ float p[SS]; __shared__ float red[SS]; __shared__ float rr[D2];
  int b=blockIdx.x, tid=threadIdx.x;
  if (tid<EE){ sBl[tid]=sB[(size_t)b*EE+tid]; vcl[tid]=vc[tid]; }
  __syncthreads();
  const float* rowA = sA + ((size_t)b*SS+tid)*EE;
  float sc=0.f;
  #pragma unroll
  for (int e=0;e<EE;e+=4){
    float4 a=*(const float4*)(rowA+e);
    float4 bb=*(const float4*)(sBl+e);
    float4 vw=*(const float4*)(vcl+e);
    sc += vw.x*(a.x+bb.x)+vw.y*(a.y+bb.y)+vw.z*(a.z+bb.z)+vw.w*(a.w+bb.w);
  }
  softmax256(sc, red, p);
  float o=0.f;
  for (int s=0;s<SS;s++) o += p[s]*agg_rep[((size_t)b*SS+s)*D2+tid];
  rr[tid]=o; __syncthreads();
  if (tid<LL){
    float a=0.f;
    const float* wr = Wpred + (size_t)tid*D2;
    for (int d=0;d<D2;d++) a += wr[d]*rr[d];
    out[(size_t)b*LL+tid]=sigmoidf_(a);
  }
}

extern "C" void kernel_launch(void* const* d_in, const int* in_sizes, int n_in,
                              void* d_out, int out_size, void* d_ws, size_t ws_size,
                              hipStream_t stream){
  (void)in_sizes; (void)n_in; (void)out_size; (void)ws_size;
  const int*   inp = (const int*)d_in[0];
  const float* emb = (const float*)d_in[1];
  const float* enc_wih_f=(const float*)d_in[2],  *enc_whh_f=(const float*)d_in[3],
             *enc_bih_f=(const float*)d_in[4],  *enc_bhh_f=(const float*)d_in[5];
  const float* enc_wih_b=(const float*)d_in[6],  *enc_whh_b=(const float*)d_in[7],
             *enc_bih_b=(const float*)d_in[8],  *enc_bhh_b=(const float*)d_in[9];
  const float* hid_wih_f=(const float*)d_in[10], *hid_whh_f=(const float*)d_in[11],
             *hid_bih_f=(const float*)d_in[12], *hid_bhh_f=(const float*)d_in[13];
  const float* hid_wih_b=(const float*)d_in[14], *hid_whh_b=(const float*)d_in[15],
             *hid_bih_b=(const float*)d_in[16], *hid_bhh_b=(const float*)d_in[17];
  const float* agg_wih_f=(const float*)d_in[18], *agg_whh_f=(const float*)d_in[19],
             *agg_bih_f=(const float*)d_in[20], *agg_bhh_f=(const float*)d_in[21];
  const float* agg_wih_b=(const float*)d_in[22], *agg_whh_b=(const float*)d_in[23],
             *agg_bih_b=(const float*)d_in[24], *agg_bhh_b=(const float*)d_in[25];
  const float* Wc1=(const float*)d_in[26], *Wc2=(const float*)d_in[27], *vc=(const float*)d_in[28];
  const float* Wb =(const float*)d_in[29];
  const float* Wd =(const float*)d_in[30], *vd=(const float*)d_in[31];
  const float* Wm =(const float*)d_in[32], *vm=(const float*)d_in[33];
  const float* Ws =(const float*)d_in[34], *vs=(const float*)d_in[35];
  const float* Wp =(const float*)d_in[36], *vp=(const float*)d_in[37];
  const float* Wpred=(const float*)d_in[38];

  float* ws = (float*)d_ws;
  size_t o = 0;
  float* gxf     = ws + o; o += (size_t)BB*SS*H3;
  float* gxb     = ws + o; o += (size_t)BB*SS*H3;
  float* hp      = ws + o; o += (size_t)BB*SS*D2;
  float* hq      = ws + o; o += (size_t)BB*SS*D2;
  float* hidden  = ws + o; o += (size_t)2*BB*EE;
  float* s1      = ws + o; o += (size_t)BB*SS*EE;
  float* s2      = ws + o; o += (size_t)BB*SS*EE;
  float* Am      = ws + o; o += (size_t)BB*SS*EE;
  float* Bm      = ws + o; o += (size_t)BB*SS*EE;
  float* Pb      = ws + o; o += (size_t)BB*SS*D2;
  float* spj     = ws + o; o += (size_t)BB*SS*EE;
  float* agg_rep = ws + o; o += (size_t)BB*SS*D2;
  float* sA      = ws + o; o += (size_t)BB*SS*EE;
  float* sB      = ws + o; o += (size_t)BB*EE;
  // bf16 buffers (ushort counts, all even -> advance o by count/2)
  unsigned short* x_bf      = (unsigned short*)(ws+o); o += (size_t)BB*SS*DP/2;
  unsigned short* hp_bf     = (unsigned short*)(ws+o); o += (size_t)BB*SS*D2/2;
  unsigned short* hq_bf     = (unsigned short*)(ws+o); o += (size_t)BB*SS*D2/2;
  unsigned short* agg_bf    = (unsigned short*)(ws+o); o += (size_t)BB*SS*D12/2;
  unsigned short* aggrep_bf = (unsigned short*)(ws+o); o += (size_t)BB*SS*D2/2;
  unsigned short* encf_bf   = (unsigned short*)(ws+o); o += (size_t)H3*DP/2;
  unsigned short* encb_bf   = (unsigned short*)(ws+o); o += (size_t)H3*DP/2;
  unsigned short* hidf_bf   = (unsigned short*)(ws+o); o += (size_t)H3*D2/2;
  unsigned short* hidb_bf   = (unsigned short*)(ws+o); o += (size_t)H3*D2/2;
  unsigned short* aggf_bf   = (unsigned short*)(ws+o); o += (size_t)H3*D12/2;
  unsigned short* aggb_bf   = (unsigned short*)(ws+o); o += (size_t)H3*D12/2;
  unsigned short* Wc1_bf    = (unsigned short*)(ws+o); o += (size_t)EE*D2/2;
  unsigned short* Wc2_bf    = (unsigned short*)(ws+o); o += (size_t)EE*D2/2;
  unsigned short* Wm_bf     = (unsigned short*)(ws+o); o += (size_t)EE*D2/2;
  unsigned short* Wb_bf     = (unsigned short*)(ws+o); o += (size_t)D2*D2/2;
  unsigned short* Wp_bf     = (unsigned short*)(ws+o); o += (size_t)EE*D2/2;
  unsigned short* Wd_bf     = (unsigned short*)(ws+o); o += (size_t)EE*D2/2;
  unsigned short* Ws_bf     = (unsigned short*)(ws+o); o += (size_t)EE*D2/2;

  const int M = BB*SS; // 1024
  auto mmbf=[&](const unsigned short* X,const unsigned short* W,const float* bias,
                float* outp,int N,int K,int z,int kspan){
    dim3 g(N/32, M/64, z);
    k_mmbf<<<g,64,0,stream>>>(X,W,bias,outp,N,K,kspan);
  };

  // ---- input prep ----
  k_embed<<<M,256,0,stream>>>(inp, emb, x_bf);
  CvtArgs ca;
  ca.s[0]  = {enc_wih_f, encf_bf, H3, DD, DP};
  ca.s[1]  = {enc_wih_b, encb_bf, H3, DD, DP};
  ca.s[2]  = {hid_wih_f, hidf_bf, H3, D2, D2};
  ca.s[3]  = {hid_wih_b, hidb_bf, H3, D2, D2};
  ca.s[4]  = {agg_wih_f, aggf_bf, H3, D12, D12};
  ca.s[5]  = {agg_wih_b, aggb_bf, H3, D12, D12};
  ca.s[6]  = {Wc1, Wc1_bf, EE, D2, D2};
  ca.s[7]  = {Wc2, Wc2_bf, EE, D2, D2};
  ca.s[8]  = {Wm,  Wm_bf,  EE, D2, D2};
  ca.s[9]  = {Wb,  Wb_bf,  D2, D2, D2};
  ca.s[10] = {Wp,  Wp_bf,  EE, D2, D2};
  ca.s[11] = {Wd,  Wd_bf,  EE, D2, D2};
  ca.s[12] = {Ws,  Ws_bf,  EE, D2, D2};
  {
    int maxpairs = H3*D12/2;  // 294912
    dim3 g((maxpairs+255)/256, 13);
    k_cvt_weights<<<g,256,0,stream>>>(ca);
  }

  // ---- encoder BiGRU ----
  k_init2<<<M,H3,0,stream>>>(gxf, enc_bih_f, gxb, enc_bih_b);
  mmbf(x_bf, encf_bf, nullptr, gxf, H3, DP, 4, 80);
  mmbf(x_bf, encb_bf, nullptr, gxb, H3, DP, 4, 80);
  k_gru_scan<<<dim3(2),512,0,stream>>>(gxf,gxb,enc_whh_f,enc_whh_b,enc_bhh_f,enc_bhh_b,
                                       nullptr,hp,hidden);
  k_cvt_bf16<<<(M*D2/2+255)/256,256,0,stream>>>(hp, hp_bf, M*D2/2);

  // ---- hidden BiGRU ----
  k_init2<<<M,H3,0,stream>>>(gxf, hid_bih_f, gxb, hid_bih_b);
  mmbf(hp_bf, hidf_bf, nullptr, gxf, H3, D2, 4, 64);
  mmbf(hp_bf, hidb_bf, nullptr, gxb, H3, D2, 4, 64);
  k_gru_scan<<<dim3(2),512,0,stream>>>(gxf,gxb,hid_whh_f,hid_whh_b,hid_bhh_f,hid_bhh_b,
                                       hidden,hq,nullptr);
  k_cvt_bf16<<<(M*D2/2+255)/256,256,0,stream>>>(hq, hq_bf, M*D2/2);

  // ---- projections (ksplit=1, direct store) ----
  mmbf(hp_bf, Wc1_bf, nullptr, s1,  EE, D2, 1, D2);
  mmbf(hq_bf, Wc2_bf, nullptr, s2,  EE, D2, 1, D2);
  mmbf(hp_bf, Wm_bf,  nullptr, Am,  EE, D2, 1, D2);
  mmbf(hq_bf, Wm_bf,  nullptr, Bm,  EE, D2, 1, D2);
  mmbf(hp_bf, Wb_bf,  nullptr, Pb,  D2, D2, 1, D2);
  mmbf(hq_bf, Wp_bf,  nullptr, spj, EE, D2, 1, D2);

  // ---- attentions -> agg (bf16). slices: hq(0) pts(256) ptc(512) ptd(768) ptb(1024) ptm(1280)
  k_copy_hq<<<M,256,0,stream>>>(hq_bf, agg_bf);
  dim3 gq(SS,BB);
  k_attn_add<<<gq,256,0,stream>>>(s1,s2,vc, 1.f, hp, agg_bf, 512);
  k_attn_add<<<gq,256,0,stream>>>(Am,Bm,vm,-1.f, hp, agg_bf, 1280);
  k_attn_bil<<<gq,256,0,stream>>>(Pb,hq,hp,agg_bf,1024);
  k_mulattn_fused<<<gq,256,0,stream>>>(hp_bf,hq,Wd_bf,vd,hp,agg_bf,768);
  k_mulattn_fused<<<gq,256,0,stream>>>(hq_bf,hq,Ws_bf,vs,hq,agg_bf,256);

  // ---- aggregation BiGRU ----
  k_init2<<<M,H3,0,stream>>>(gxf, agg_bih_f, gxb, agg_bih_b);
  mmbf(agg_bf, aggf_bf, nullptr, gxf, H3, D12, 8, 192);
  mmbf(agg_bf, aggb_bf, nullptr, gxb, H3, D12, 8, 192);
  k_gru_scan<<<dim3(2),512,0,stream>>>(gxf,gxb,agg_whh_f,agg_whh_b,agg_bhh_f,agg_bhh_b,
                                       nullptr,agg_rep,nullptr);
  k_cvt_bf16<<<(M*D2/2+255)/256,256,0,stream>>>(agg_rep, aggrep_bf, M*D2/2);

  // ---- pooling + prediction ----
  k_rl<<<BB,256,0,stream>>>(spj,hq,vp,Wc2,sB);
  mmbf(aggrep_bf, Wc1_bf, nullptr, sA, EE, D2, 1, D2);
  k_final<<<BB,256,0,stream>>>(sA,sB,vc,agg_rep,Wpred,(float*)d_out);
}